// Round 4
// baseline (663.703 us; speedup 1.0000x reference)
//
#include <hip/hip_runtime.h>
#include <hip/hip_bf16.h>

#define TOKS 16384
#define HID  4096
#define NEXP 64
#define TOKB 64
#define BH   128
#define XSTR 132     // 128+4 pad: conflict-free b128 reads down a column of rows
#define EPS  1e-4f   // flag threshold: fp32 accum err <=~5e-6, 20x margin

// ===== ws layout (floats) =====
// [0..63] prob sums | [64..127] argmax counts | int@[128] flag count |
// ints [192..192+16384) flag list | floats [16576...) partials P[kc][tok][exp]
#define WS_FLAGCNT  128
#define WS_FLAGLIST 192
#define WS_PBASE    16576

__global__ void moe_init(float* __restrict__ wsf, int n) {
    const int i = blockIdx.x * blockDim.x + threadIdx.x;
    if (i < n) wsf[i] = 0.0f;
}

// ---------- stage 1: fp32 partial GEMM, K-split via blockIdx.y ----------
// 512 thr = 8 waves; lane = token, wave owns 8 experts. W via VECTOR loads
// (vmcnt) so only the X ds_read rides lgkmcnt -> no cross-counter drains.
__global__ __launch_bounds__(512, 4)
void moe_part(const float* __restrict__ X, const float* __restrict__ W,
              float* __restrict__ P, int klen) {
    __shared__ float xs[TOKB][XSTR];
    const int tid  = threadIdx.x;
    const int lane = tid & 63;
    const int wid  = tid >> 6;            // 0..7
    const int tok0 = blockIdx.x * TOKB;
    const int kc   = blockIdx.y;
    const int k0   = kc * klen;

    // VGPR zero the compiler can't fold -> W addresses stay vector (vmcnt path)
    int vzero;
    asm volatile("v_mov_b32 %0, 0" : "=v"(vzero));

    float acc[8];
    #pragma unroll
    for (int e = 0; e < 8; ++e) acc[e] = 0.f;

    const float* wexp = W + (size_t)(wid * 8) * HID + vzero;

    for (int h0 = k0; h0 < k0 + klen; h0 += BH) {
        // stage X[64 tok][128 h]: 512 thr x 4 float4, coalesced
        #pragma unroll
        for (int p = 0; p < 4; ++p) {
            const int f   = tid + (p << 9);       // float4 index 0..2047
            const int row = f >> 5;
            const int col = (f & 31) << 2;
            *(float4*)&xs[row][col] =
                *(const float4*)&X[(size_t)(tok0 + row) * HID + h0 + col];
        }
        __syncthreads();

        const float* wb = wexp + h0;
        #pragma unroll 2
        for (int hh = 0; hh < BH; hh += 4) {
            const float4 xv = *(const float4*)&xs[lane][hh];
            #pragma unroll
            for (int e = 0; e < 8; ++e) {
                const float4 wv = *(const float4*)(wb + (size_t)e * HID + hh);
                acc[e] = fmaf(xv.x, wv.x, acc[e]);
                acc[e] = fmaf(xv.y, wv.y, acc[e]);
                acc[e] = fmaf(xv.z, wv.z, acc[e]);
                acc[e] = fmaf(xv.w, wv.w, acc[e]);
            }
        }
        __syncthreads();
    }

    // transpose through LDS -> coalesced P store
    float* xsf = &xs[0][0];  // reuse as [64][68]
    #pragma unroll
    for (int e = 0; e < 8; ++e) xsf[lane * 68 + wid * 8 + e] = acc[e];
    __syncthreads();
    {
        const int tok = tid >> 3;
        const int e0  = (tid & 7) << 3;
        float* dst = P + ((size_t)kc * TOKS + tok0 + tok) * NEXP + e0;
        const float* src = xsf + tok * 68 + e0;
        *(float4*)dst       = *(const float4*)src;
        *(float4*)(dst + 4) = *(const float4*)(src + 4);
    }
}

// ---------- stage 2: reduce partials, softmax, top-8, flag close calls ----------
template <int KS>
__global__ __launch_bounds__(256, 4)
void moe_topk(const float* __restrict__ P, float* __restrict__ out,
              float* __restrict__ wsf) {
    const int tid  = threadIdx.x;
    const int lane = tid & 63;
    const int wid  = tid >> 6;   // 0..3
    const int tok0 = blockIdx.x * 16;
    float* outIdx = out;
    float* outW   = out + TOKS * 8;
    int* flagcnt  = (int*)wsf + WS_FLAGCNT;
    int* flaglist = (int*)wsf + WS_FLAGLIST;

    float rp = 0.f;
    #pragma unroll
    for (int tt = 0; tt < 4; ++tt) {
        const int tok = tok0 + wid * 4 + tt;
        float lg = 0.f;
        #pragma unroll
        for (int kc = 0; kc < KS; ++kc)
            lg += P[((size_t)kc * TOKS + tok) * NEXP + lane];

        // wave-wide softmax (lane = expert)
        float m = lg;
        #pragma unroll
        for (int o = 32; o; o >>= 1) m = fmaxf(m, __shfl_xor(m, o, 64));
        const float p = __expf(lg - m);
        float s = p;
        #pragma unroll
        for (int o = 32; o; o >>= 1) s += __shfl_xor(s, o, 64);
        const float inv_s = 1.0f / s;
        rp += p * inv_s;

        // top-9 (9th only for membership-gap check), ties -> lower index
        float v = lg;
        float lw[9]; int ik[9];
        #pragma unroll
        for (int k = 0; k < 9; ++k) {
            float bv = v; int bi = lane;
            #pragma unroll
            for (int o = 32; o; o >>= 1) {
                const float ov = __shfl_xor(bv, o, 64);
                const int   oi = __shfl_xor(bi, o, 64);
                if (ov > bv || (ov == bv && oi < bi)) { bv = ov; bi = oi; }
            }
            lw[k] = bv; ik[k] = bi;
            if (lane == bi) v = -3.0e38f;
        }
        float mingap = 3.0e38f;
        #pragma unroll
        for (int k = 0; k < 8; ++k) mingap = fminf(mingap, lw[k] - lw[k + 1]);

        float wk[8]; float denom = 1e-20f;
        #pragma unroll
        for (int k = 0; k < 8; ++k) { wk[k] = __expf(lw[k] - m) * inv_s; denom += wk[k]; }
        const float invd = 1.0f / denom;
        const size_t base = (size_t)tok * 8;
        if (lane < 8) {
            outIdx[base + lane] = (float)ik[lane];
            outW[base + lane]   = wk[lane] * invd;
        }
        if (lane == 0) {
            atomicAdd(&wsf[NEXP + ik[0]], 1.0f);
            if (mingap < EPS) {
                const int pos = atomicAdd(flagcnt, 1);
                if (pos < TOKS) flaglist[pos] = tok;
            }
        }
    }
    atomicAdd(&wsf[lane], rp);
}

// ---------- stage 3: exact fp64 redo for flagged tokens ----------
__global__ __launch_bounds__(256, 2)
void moe_fix(const float* __restrict__ X, const float* __restrict__ W,
             float* __restrict__ out, float* __restrict__ wsf) {
    __shared__ double red[256];
    const int tid = threadIdx.x;
    const int e   = tid & 63;
    const int kc  = tid >> 6;
    const int nf  = min(*((int*)wsf + WS_FLAGCNT), TOKS);
    const int* flaglist = (const int*)wsf + WS_FLAGLIST;
    float* outIdx = out;
    float* outW   = out + TOKS * 8;

    for (int fi = blockIdx.x; fi < nf; fi += gridDim.x) {
        const int tok = flaglist[fi];
        const float* xrow = X + (size_t)tok * HID + kc * 1024;
        const float* wrow = W + (size_t)e  * HID + kc * 1024;
        double part = 0.0;
        for (int j = 0; j < 1024; j += 4) {
            const float4 xv = *(const float4*)(xrow + j);
            const float4 wv = *(const float4*)(wrow + j);
            part = fma((double)xv.x, (double)wv.x, part);
            part = fma((double)xv.y, (double)wv.y, part);
            part = fma((double)xv.z, (double)wv.z, part);
            part = fma((double)xv.w, (double)wv.w, part);
        }
        red[tid] = part;
        __syncthreads();
        if (tid < 64) {   // wave 0, lane = expert
            const double lg = ((red[tid] + red[64 + tid]) + red[128 + tid]) + red[192 + tid];
            const float lgf = (float)lg;
            float m = lgf;
            #pragma unroll
            for (int o = 32; o; o >>= 1) m = fmaxf(m, __shfl_xor(m, o, 64));
            const float p = __expf(lgf - m);
            float s = p;
            #pragma unroll
            for (int o = 32; o; o >>= 1) s += __shfl_xor(s, o, 64);
            const float inv_s = 1.0f / s;

            double v = lg;
            double bw[8]; int ik[8];
            #pragma unroll
            for (int k = 0; k < 8; ++k) {
                double bv = v; int bi = tid;
                #pragma unroll
                for (int o = 32; o; o >>= 1) {
                    const double ov = __shfl_xor(bv, o, 64);
                    const int    oi = __shfl_xor(bi, o, 64);
                    if (ov > bv || (ov == bv && oi < bi)) { bv = ov; bi = oi; }
                }
                bw[k] = bv; ik[k] = bi;
                if (tid == bi) v = -1.0e300;
            }
            float wk[8]; float denom = 1e-20f;
            #pragma unroll
            for (int k = 0; k < 8; ++k) {
                wk[k] = __expf((float)bw[k] - m) * inv_s; denom += wk[k];
            }
            const float invd = 1.0f / denom;
            const size_t base = (size_t)tok * 8;
            const int oldtop = (int)outIdx[base];
            if (tid < 8) {
                outIdx[base + tid] = (float)ik[tid];
                outW[base + tid]   = wk[tid] * invd;
            }
            if (tid == 0 && ik[0] != oldtop) {
                atomicAdd(&wsf[NEXP + oldtop], -1.0f);
                atomicAdd(&wsf[NEXP + ik[0]],  1.0f);
            }
        }
        __syncthreads();
    }
}

__global__ void moe_final(const float* __restrict__ wsf, float* __restrict__ out) {
    const int e = threadIdx.x;  // 64 threads
    float v = wsf[e] * wsf[NEXP + e];
    #pragma unroll
    for (int o = 32; o; o >>= 1) v += __shfl_xor(v, o, 64);
    if (e == 0)
        out[2 * TOKS * 8] = v * (64.0f / ((float)TOKS * (float)TOKS));
}

// ===== fallback monolith (proven R2 path) for small ws =====
__global__ void moe_w_cvt(const float* __restrict__ W, double* __restrict__ Wd) {
    const int i = blockIdx.x * blockDim.x + threadIdx.x;
    if (i < NEXP * HID) Wd[i] = (double)W[i];
}

__global__ __launch_bounds__(512, 2)
void moe_mono(const float* __restrict__ X, const double* __restrict__ Wd,
              float* __restrict__ out, float* __restrict__ wsf) {
    __shared__ double xs[TOKB][66];
    __shared__ double L[TOKB][65];
    const int tid  = threadIdx.x;
    const int lane = tid & 63;
    const int wid  = __builtin_amdgcn_readfirstlane(tid >> 6);
    const int tok0 = blockIdx.x * TOKB;
    double acc[8] = {0., 0., 0., 0., 0., 0., 0., 0.};
    for (int h0 = 0; h0 < HID; h0 += 64) {
        #pragma unroll
        for (int i = 0; i < 8; ++i) {
            const int li = tid + i * 512;
            xs[li >> 6][li & 63] = (double)X[((size_t)(tok0 + (li >> 6)) << 12) + (h0 + (li & 63))];
        }
        __syncthreads();
        const double* wchunk = Wd + (((size_t)(wid << 3)) << 12) + h0;
        #pragma unroll 2
        for (int hh = 0; hh < 64; hh += 2) {
            const double2 xv = *(const double2*)&xs[lane][hh];
            #pragma unroll
            for (int e = 0; e < 8; ++e) {
                const double* wr = wchunk + (((size_t)e) << 12) + hh;
                acc[e] = fma(xv.x, wr[0], acc[e]);
                acc[e] = fma(xv.y, wr[1], acc[e]);
            }
        }
        __syncthreads();
    }
    #pragma unroll
    for (int e = 0; e < 8; ++e) L[lane][(wid << 3) + e] = acc[e];
    __syncthreads();
    float* outIdx = out;
    float* outW   = out + (TOKS * 8);
    float rp = 0.0f;
    for (int tt = 0; tt < 8; ++tt) {
        const int t = (wid << 3) + tt;
        const double lg = L[t][lane];
        const float lgf = (float)lg;
        float m = lgf;
        #pragma unroll
        for (int o = 32; o; o >>= 1) m = fmaxf(m, __shfl_xor(m, o, 64));
        const float p = __expf(lgf - m);
        float s = p;
        #pragma unroll
        for (int o = 32; o; o >>= 1) s += __shfl_xor(s, o, 64);
        const float inv_s = 1.0f / s;
        rp += p * inv_s;
        double v = lg;
        float wk[8]; int ik[8];
        #pragma unroll
        for (int k = 0; k < 8; ++k) {
            double bv = v; int bi = lane;
            #pragma unroll
            for (int o = 32; o; o >>= 1) {
                const double ov = __shfl_xor(bv, o, 64);
                const int    oi = __shfl_xor(bi, o, 64);
                if (ov > bv || (ov == bv && oi < bi)) { bv = ov; bi = oi; }
            }
            wk[k] = __expf((float)bv - m) * inv_s; ik[k] = bi;
            if (lane == bi) v = -1.0e300;
        }
        if (lane == 0) {
            const float denom = (((wk[0]+wk[1])+(wk[2]+wk[3])) +
                                 ((wk[4]+wk[5])+(wk[6]+wk[7]))) + 1e-20f;
            const float invd = 1.0f / denom;
            const size_t base = ((size_t)(tok0 + t)) << 3;
            #pragma unroll
            for (int k = 0; k < 8; ++k) {
                outIdx[base + k] = (float)ik[k];
                outW[base + k]   = wk[k] * invd;
            }
            atomicAdd(&wsf[NEXP + ik[0]], 1.0f);
        }
    }
    atomicAdd(&wsf[lane], rp);
}

extern "C" void kernel_launch(void* const* d_in, const int* in_sizes, int n_in,
                              void* d_out, int out_size, void* d_ws, size_t ws_size,
                              hipStream_t stream) {
    const float* X = (const float*)d_in[0];   // [4,4096,4096] fp32
    const float* W = (const float*)d_in[1];   // [64,4096] fp32
    float* out = (float*)d_out;
    float* wsf = (float*)d_ws;

    int KS = 0;
    if      (ws_size >= 4ull * (WS_PBASE + 2ull * TOKS * NEXP)) KS = 2;
    else if (ws_size >= 4ull * (WS_PBASE + 1ull * TOKS * NEXP)) KS = 1;

    if (KS > 0) {
        float* P = wsf + WS_PBASE;
        moe_init<<<1, 256, 0, stream>>>(wsf, 192);
        dim3 g1(TOKS / TOKB, KS);
        moe_part<<<g1, 512, 0, stream>>>(X, W, P, HID / KS);
        if (KS == 2) moe_topk<2><<<TOKS / 16, 256, 0, stream>>>(P, out, wsf);
        else         moe_topk<1><<<TOKS / 16, 256, 0, stream>>>(P, out, wsf);
        moe_fix<<<256, 256, 0, stream>>>(X, W, out, wsf);
        moe_final<<<1, 64, 0, stream>>>(wsf, out);
    } else {
        double* Wd = (double*)d_ws;
        float* wsf2 = (float*)(Wd + NEXP * HID);
        moe_w_cvt<<<(NEXP * HID + 255) / 256, 256, 0, stream>>>(W, Wd);
        moe_init<<<1, 256, 0, stream>>>(wsf2, 128);
        moe_mono<<<TOKS / TOKB, 512, 0, stream>>>(X, Wd, out, wsf2);
        moe_final<<<1, 64, 0, stream>>>(wsf2, out);
    }
}

// Round 5
// 279.794 us; speedup vs baseline: 2.3721x; 2.3721x over previous
//
#include <hip/hip_runtime.h>
#include <hip/hip_bf16.h>

#define TOKS 16384
#define HID  4096
#define NEXP 64
#define EPS  1e-4f   // flag threshold; bf16-split logit err ~2.4e-6 -> 40x margin

// ===== ws layout (floats) =====
// [0..63] prob sums | [64..127] argmax counts | int@[128] flag count |
// ints [192..192+16384) flag list | [16576) Bpack (1 MB = 262144 floats) |
// [278720) partials P[kc][tok][exp] (2 x 16384 x 64 floats)
#define WS_FLAGCNT  128
#define WS_FLAGLIST 192
#define WS_BPACK    16576
#define WS_PBASE    278720
#define BPK_LO      262144   // ushort offset of lo array inside Bpack

typedef __attribute__((ext_vector_type(8))) short short8_t;
typedef __attribute__((ext_vector_type(4))) float f32x4;

static __device__ __forceinline__ unsigned short f2bf_rn(float x) {
    unsigned u = __builtin_bit_cast(unsigned, x);
    u = (u + 0x7fffu + ((u >> 16) & 1u)) >> 16;
    return (unsigned short)u;
}
static __device__ __forceinline__ float bf2f(unsigned short h) {
    return __builtin_bit_cast(float, (unsigned)h << 16);
}

__global__ void moe_init(float* __restrict__ wsf, int n) {
    const int i = blockIdx.x * blockDim.x + threadIdx.x;
    if (i < n) wsf[i] = 0.0f;
}

// ---------- prep: W -> frag-ready bf16 hi/lo pack; also zero reduction slots ----------
// Bpack[kt 0..127][nt 0..3][lane 0..63][j 0..7] = Wsplit[n = nt*16 + (lane&15)][k = kt*32 + 8*(lane>>4) + j]
__global__ void moe_prep(const float* __restrict__ W, unsigned short* __restrict__ Bpk,
                         float* __restrict__ wsf) {
    const int idx = blockIdx.x * blockDim.x + threadIdx.x;
    if (idx < 192) wsf[idx] = 0.0f;
    if (idx >= NEXP * HID) return;
    const int n = idx >> 12;          // expert
    const int k = idx & 4095;
    const float w = W[idx];
    const unsigned short hi = f2bf_rn(w);
    const unsigned short lo = f2bf_rn(w - bf2f(hi));
    const int kt   = k >> 5;
    const int nt   = n >> 4;
    const int lane = (n & 15) | (((k >> 3) & 3) << 4);
    const int j    = k & 7;
    const int dst  = (((kt << 2) + nt) << 9) + (lane << 3) + j;
    Bpk[dst]          = hi;
    Bpk[BPK_LO + dst] = lo;
}

// ---------- stage 1: bf16-split MFMA GEMM, K-split via blockIdx.y ----------
// Block: 128 thr = 2 waves, 32 tokens (16/wave). Wave: M=16 tok, N=64 (4 ntiles), K=2048.
__global__ __launch_bounds__(128, 4)
void moe_mfma(const float* __restrict__ X, const unsigned short* __restrict__ Bpk,
              float* __restrict__ P) {
    __shared__ __align__(16) unsigned short xhi[32][72];
    __shared__ __align__(16) unsigned short xlo[32][72];
    const int tid  = threadIdx.x;
    const int lane = tid & 63;
    const int wid  = tid >> 6;             // 0..1
    const int tok0 = blockIdx.x * 32;
    const int kc   = blockIdx.y;           // 0..1
    const int k0b  = kc * 2048;

    f32x4 acc[4];
    #pragma unroll
    for (int nt = 0; nt < 4; ++nt) acc[nt] = (f32x4){0.f, 0.f, 0.f, 0.f};

    const int arow = (wid << 4) + (lane & 15);
    const int aoff = (lane >> 4) << 3;     // 8*(lane>>4)

    for (int kk = 0; kk < 2048; kk += 64) {
        // stage X[32 tok][64 h] fp32 -> bf16 hi/lo in LDS
        #pragma unroll
        for (int p = 0; p < 4; ++p) {
            const int f   = tid + (p << 7);
            const int row = f >> 4;
            const int c   = (f & 15) << 2;
            const float4 gx = *(const float4*)&X[(size_t)(tok0 + row) * HID + k0b + kk + c];
            ushort4 h, l;
            h.x = f2bf_rn(gx.x); l.x = f2bf_rn(gx.x - bf2f(h.x));
            h.y = f2bf_rn(gx.y); l.y = f2bf_rn(gx.y - bf2f(h.y));
            h.z = f2bf_rn(gx.z); l.z = f2bf_rn(gx.z - bf2f(h.z));
            h.w = f2bf_rn(gx.w); l.w = f2bf_rn(gx.w - bf2f(h.w));
            *(ushort4*)&xhi[row][c] = h;
            *(ushort4*)&xlo[row][c] = l;
        }
        __syncthreads();

        #pragma unroll
        for (int s = 0; s < 2; ++s) {
            const int kt = (k0b + kk + (s << 5)) >> 5;
            const short8_t ah = *(const short8_t*)&xhi[arow][(s << 5) + aoff];
            const short8_t al = *(const short8_t*)&xlo[arow][(s << 5) + aoff];
            const unsigned short* bb = Bpk + ((size_t)(kt << 2) << 9) + (lane << 3);
            #pragma unroll
            for (int nt = 0; nt < 4; ++nt) {
                const short8_t bh = *(const short8_t*)(bb + (nt << 9));
                const short8_t bl = *(const short8_t*)(bb + BPK_LO + (nt << 9));
                acc[nt] = __builtin_amdgcn_mfma_f32_16x16x32_bf16(ah, bh, acc[nt], 0, 0, 0);
                acc[nt] = __builtin_amdgcn_mfma_f32_16x16x32_bf16(al, bh, acc[nt], 0, 0, 0);
                acc[nt] = __builtin_amdgcn_mfma_f32_16x16x32_bf16(ah, bl, acc[nt], 0, 0, 0);
            }
        }
        __syncthreads();
    }

    // C/D: col = lane&15 (expert within ntile), row = (lane>>4)*4 + r (token)
    const int prow0 = tok0 + (wid << 4) + ((lane >> 4) << 2);
    const int pexp  = lane & 15;
    #pragma unroll
    for (int nt = 0; nt < 4; ++nt)
        #pragma unroll
        for (int r = 0; r < 4; ++r)
            P[((size_t)kc * TOKS + prow0 + r) * NEXP + (nt << 4) + pexp] = acc[nt][r];
}

// ---------- stage 2: reduce partials, softmax, top-8, flag close calls ----------
template <int KS>
__global__ __launch_bounds__(256, 4)
void moe_topk(const float* __restrict__ P, float* __restrict__ out,
              float* __restrict__ wsf) {
    const int tid  = threadIdx.x;
    const int lane = tid & 63;
    const int wid  = tid >> 6;   // 0..3
    const int tok0 = blockIdx.x * 16;
    float* outIdx = out;
    float* outW   = out + TOKS * 8;
    int* flagcnt  = (int*)wsf + WS_FLAGCNT;
    int* flaglist = (int*)wsf + WS_FLAGLIST;

    float rp = 0.f;
    #pragma unroll
    for (int tt = 0; tt < 4; ++tt) {
        const int tok = tok0 + wid * 4 + tt;
        float lg = 0.f;
        #pragma unroll
        for (int kc = 0; kc < KS; ++kc)
            lg += P[((size_t)kc * TOKS + tok) * NEXP + lane];

        // wave-wide softmax (lane = expert)
        float m = lg;
        #pragma unroll
        for (int o = 32; o; o >>= 1) m = fmaxf(m, __shfl_xor(m, o, 64));
        const float p = __expf(lg - m);
        float s = p;
        #pragma unroll
        for (int o = 32; o; o >>= 1) s += __shfl_xor(s, o, 64);
        const float inv_s = 1.0f / s;
        rp += p * inv_s;

        // top-9 (9th only for membership-gap check), ties -> lower index
        float v = lg;
        float lw[9]; int ik[9];
        #pragma unroll
        for (int k = 0; k < 9; ++k) {
            float bv = v; int bi = lane;
            #pragma unroll
            for (int o = 32; o; o >>= 1) {
                const float ov = __shfl_xor(bv, o, 64);
                const int   oi = __shfl_xor(bi, o, 64);
                if (ov > bv || (ov == bv && oi < bi)) { bv = ov; bi = oi; }
            }
            lw[k] = bv; ik[k] = bi;
            if (lane == bi) v = -3.0e38f;
        }
        float mingap = 3.0e38f;
        #pragma unroll
        for (int k = 0; k < 8; ++k) mingap = fminf(mingap, lw[k] - lw[k + 1]);

        float wk[8]; float denom = 1e-20f;
        #pragma unroll
        for (int k = 0; k < 8; ++k) { wk[k] = __expf(lw[k] - m) * inv_s; denom += wk[k]; }
        const float invd = 1.0f / denom;
        const size_t base = (size_t)tok * 8;
        if (lane < 8) {
            outIdx[base + lane] = (float)ik[lane];
            outW[base + lane]   = wk[lane] * invd;
        }
        if (lane == 0) {
            atomicAdd(&wsf[NEXP + ik[0]], 1.0f);
            if (mingap < EPS) {
                const int pos = atomicAdd(flagcnt, 1);
                if (pos < TOKS) flaglist[pos] = tok;
            }
        }
    }
    atomicAdd(&wsf[lane], rp);
}

// ---------- stage 3: exact fp64 redo for flagged tokens ----------
__global__ __launch_bounds__(256, 2)
void moe_fix(const float* __restrict__ X, const float* __restrict__ W,
             float* __restrict__ out, float* __restrict__ wsf) {
    __shared__ double red[256];
    const int tid = threadIdx.x;
    const int e   = tid & 63;
    const int kc  = tid >> 6;
    const int nf  = min(*((int*)wsf + WS_FLAGCNT), TOKS);
    const int* flaglist = (const int*)wsf + WS_FLAGLIST;
    float* outIdx = out;
    float* outW   = out + TOKS * 8;

    for (int fi = blockIdx.x; fi < nf; fi += gridDim.x) {
        const int tok = flaglist[fi];
        const float* xrow = X + (size_t)tok * HID + kc * 1024;
        const float* wrow = W + (size_t)e  * HID + kc * 1024;
        double part = 0.0;
        for (int j = 0; j < 1024; j += 4) {
            const float4 xv = *(const float4*)(xrow + j);
            const float4 wv = *(const float4*)(wrow + j);
            part = fma((double)xv.x, (double)wv.x, part);
            part = fma((double)xv.y, (double)wv.y, part);
            part = fma((double)xv.z, (double)wv.z, part);
            part = fma((double)xv.w, (double)wv.w, part);
        }
        red[tid] = part;
        __syncthreads();
        if (tid < 64) {   // wave 0, lane = expert
            const double lg = ((red[tid] + red[64 + tid]) + red[128 + tid]) + red[192 + tid];
            const float lgf = (float)lg;
            float m = lgf;
            #pragma unroll
            for (int o = 32; o; o >>= 1) m = fmaxf(m, __shfl_xor(m, o, 64));
            const float p = __expf(lgf - m);
            float s = p;
            #pragma unroll
            for (int o = 32; o; o >>= 1) s += __shfl_xor(s, o, 64);
            const float inv_s = 1.0f / s;

            double v = lg;
            double bw[8]; int ik[8];
            #pragma unroll
            for (int k = 0; k < 8; ++k) {
                double bv = v; int bi = tid;
                #pragma unroll
                for (int o = 32; o; o >>= 1) {
                    const double ov = __shfl_xor(bv, o, 64);
                    const int    oi = __shfl_xor(bi, o, 64);
                    if (ov > bv || (ov == bv && oi < bi)) { bv = ov; bi = oi; }
                }
                bw[k] = bv; ik[k] = bi;
                if (tid == bi) v = -1.0e300;
            }
            float wk[8]; float denom = 1e-20f;
            #pragma unroll
            for (int k = 0; k < 8; ++k) {
                wk[k] = __expf((float)bw[k] - m) * inv_s; denom += wk[k];
            }
            const float invd = 1.0f / denom;
            const size_t base = (size_t)tok * 8;
            const int oldtop = (int)outIdx[base];
            if (tid < 8) {
                outIdx[base + tid] = (float)ik[tid];
                outW[base + tid]   = wk[tid] * invd;
            }
            if (tid == 0 && ik[0] != oldtop) {
                atomicAdd(&wsf[NEXP + oldtop], -1.0f);
                atomicAdd(&wsf[NEXP + ik[0]],  1.0f);
            }
        }
        __syncthreads();
    }
}

__global__ void moe_final(const float* __restrict__ wsf, float* __restrict__ out) {
    const int e = threadIdx.x;  // 64 threads
    float v = wsf[e] * wsf[NEXP + e];
    #pragma unroll
    for (int o = 32; o; o >>= 1) v += __shfl_xor(v, o, 64);
    if (e == 0)
        out[2 * TOKS * 8] = v * (64.0f / ((float)TOKS * (float)TOKS));
}

// ===== fallback monolith (proven R2 path) for small ws =====
__global__ void moe_w_cvt(const float* __restrict__ W, double* __restrict__ Wd) {
    const int i = blockIdx.x * blockDim.x + threadIdx.x;
    if (i < NEXP * HID) Wd[i] = (double)W[i];
}

__global__ __launch_bounds__(512, 2)
void moe_mono(const float* __restrict__ X, const double* __restrict__ Wd,
              float* __restrict__ out, float* __restrict__ wsf) {
    __shared__ double xs[64][66];
    __shared__ double L[64][65];
    const int tid  = threadIdx.x;
    const int lane = tid & 63;
    const int wid  = __builtin_amdgcn_readfirstlane(tid >> 6);
    const int tok0 = blockIdx.x * 64;
    double acc[8] = {0., 0., 0., 0., 0., 0., 0., 0.};
    for (int h0 = 0; h0 < HID; h0 += 64) {
        #pragma unroll
        for (int i = 0; i < 8; ++i) {
            const int li = tid + i * 512;
            xs[li >> 6][li & 63] = (double)X[((size_t)(tok0 + (li >> 6)) << 12) + (h0 + (li & 63))];
        }
        __syncthreads();
        const double* wchunk = Wd + (((size_t)(wid << 3)) << 12) + h0;
        #pragma unroll 2
        for (int hh = 0; hh < 64; hh += 2) {
            const double2 xv = *(const double2*)&xs[lane][hh];
            #pragma unroll
            for (int e = 0; e < 8; ++e) {
                const double* wr = wchunk + (((size_t)e) << 12) + hh;
                acc[e] = fma(xv.x, wr[0], acc[e]);
                acc[e] = fma(xv.y, wr[1], acc[e]);
            }
        }
        __syncthreads();
    }
    #pragma unroll
    for (int e = 0; e < 8; ++e) L[lane][(wid << 3) + e] = acc[e];
    __syncthreads();
    float* outIdx = out;
    float* outW   = out + (TOKS * 8);
    float rp = 0.0f;
    for (int tt = 0; tt < 8; ++tt) {
        const int t = (wid << 3) + tt;
        const double lg = L[t][lane];
        const float lgf = (float)lg;
        float m = lgf;
        #pragma unroll
        for (int o = 32; o; o >>= 1) m = fmaxf(m, __shfl_xor(m, o, 64));
        const float p = __expf(lgf - m);
        float s = p;
        #pragma unroll
        for (int o = 32; o; o >>= 1) s += __shfl_xor(s, o, 64);
        const float inv_s = 1.0f / s;
        rp += p * inv_s;
        double v = lg;
        float wk[8]; int ik[8];
        #pragma unroll
        for (int k = 0; k < 8; ++k) {
            double bv = v; int bi = lane;
            #pragma unroll
            for (int o = 32; o; o >>= 1) {
                const double ov = __shfl_xor(bv, o, 64);
                const int    oi = __shfl_xor(bi, o, 64);
                if (ov > bv || (ov == bv && oi < bi)) { bv = ov; bi = oi; }
            }
            wk[k] = __expf((float)bv - m) * inv_s; ik[k] = bi;
            if (lane == bi) v = -1.0e300;
        }
        if (lane == 0) {
            const float denom = (((wk[0]+wk[1])+(wk[2]+wk[3])) +
                                 ((wk[4]+wk[5])+(wk[6]+wk[7]))) + 1e-20f;
            const float invd = 1.0f / denom;
            const size_t base = ((size_t)(tok0 + t)) << 3;
            #pragma unroll
            for (int k = 0; k < 8; ++k) {
                outIdx[base + k] = (float)ik[k];
                outW[base + k]   = wk[k] * invd;
            }
            atomicAdd(&wsf[NEXP + ik[0]], 1.0f);
        }
    }
    atomicAdd(&wsf[lane], rp);
}

extern "C" void kernel_launch(void* const* d_in, const int* in_sizes, int n_in,
                              void* d_out, int out_size, void* d_ws, size_t ws_size,
                              hipStream_t stream) {
    const float* X = (const float*)d_in[0];   // [4,4096,4096] fp32
    const float* W = (const float*)d_in[1];   // [64,4096] fp32
    float* out = (float*)d_out;
    float* wsf = (float*)d_ws;

    const size_t need = 4ull * (WS_PBASE + 2ull * TOKS * NEXP);  // ~9.5 MB

    if (ws_size >= need) {
        unsigned short* Bpk = (unsigned short*)(wsf + WS_BPACK);
        float* P = wsf + WS_PBASE;
        moe_prep<<<(NEXP * HID + 255) / 256, 256, 0, stream>>>(W, Bpk, wsf);
        dim3 g1(TOKS / 32, 2);
        moe_mfma<<<g1, 128, 0, stream>>>(X, Bpk, P);
        moe_topk<2><<<TOKS / 16, 256, 0, stream>>>(P, out, wsf);
        moe_fix<<<256, 256, 0, stream>>>(X, W, out, wsf);
        moe_final<<<1, 64, 0, stream>>>(wsf, out);
    } else {
        double* Wd = (double*)d_ws;
        float* wsf2 = (float*)(Wd + NEXP * HID);
        moe_w_cvt<<<(NEXP * HID + 255) / 256, 256, 0, stream>>>(W, Wd);
        moe_init<<<1, 256, 0, stream>>>(wsf2, 128);
        moe_mono<<<TOKS / 64, 512, 0, stream>>>(X, Wd, out, wsf2);
        moe_final<<<1, 64, 0, stream>>>(wsf2, out);
    }
}

// Round 6
// 276.717 us; speedup vs baseline: 2.3985x; 1.0111x over previous
//
#include <hip/hip_runtime.h>
#include <hip/hip_bf16.h>

#define TOKS 16384
#define HID  4096
#define NEXP 64
#define EPS  1e-4f   // flag threshold; bf16-split logit err ~3e-6 -> 30x margin

// ===== ws layout (floats) =====
// [0..63] prob sums | [64..127] argmax counts | int@[128] flag count |
// ints [192..192+16384) flag list | [16576) Bpack (1 MB, bf16 hi/lo frag-packed)
#define WS_FLAGCNT  128
#define WS_FLAGLIST 192
#define WS_BPACK    16576
#define BPK_LO      262144   // ushort offset of lo plane inside Bpack

typedef __attribute__((ext_vector_type(8))) short short8_t;
typedef __attribute__((ext_vector_type(4))) float f32x4;

static __device__ __forceinline__ unsigned short f2bf_rn(float x) {
    unsigned u = __builtin_bit_cast(unsigned, x);
    u = (u + 0x7fffu + ((u >> 16) & 1u)) >> 16;
    return (unsigned short)u;
}
static __device__ __forceinline__ float bf2f(unsigned short h) {
    return __builtin_bit_cast(float, (unsigned)h << 16);
}

// ---------- prep: W -> frag-ready bf16 hi/lo pack; zero reduction slots ----------
// Bpack[kt 0..127][nt 0..3][lane 0..63][j 0..7] = Wsplit[n=nt*16+(lane&15)][k=kt*32+8*(lane>>4)+j]
__global__ void moe_prep(const float* __restrict__ W, unsigned short* __restrict__ Bpk,
                         float* __restrict__ wsf) {
    const int idx = blockIdx.x * blockDim.x + threadIdx.x;
    if (idx < 192) wsf[idx] = 0.0f;
    if (idx >= NEXP * HID) return;
    const int n = idx >> 12;
    const int k = idx & 4095;
    const float w = W[idx];
    const unsigned short hi = f2bf_rn(w);
    const unsigned short lo = f2bf_rn(w - bf2f(hi));
    const int kt   = k >> 5;
    const int nt   = n >> 4;
    const int lane = (n & 15) | (((k >> 3) & 3) << 4);
    const int j    = k & 7;
    const int dst  = (((kt << 2) + nt) << 9) + (lane << 3) + j;
    Bpk[dst]          = hi;
    Bpk[BPK_LO + dst] = lo;
}

// ---------- fused: bf16-split MFMA GEMM + softmax + bitonic top-8 + flag ----------
// 256 thr = 4 waves; 32 tokens/block. Wave w: K-half h=w>>1, token-halftile w&1 (M=16).
// LDS: double-buffered staged X (hi/lo), chunk = 64 k per K-half.
__global__ __launch_bounds__(256, 4)
void moe_fused(const float* __restrict__ X, const unsigned short* __restrict__ Bpk,
               float* __restrict__ out, float* __restrict__ wsf) {
    __shared__ __align__(16) unsigned short sbuf[2][2][32][136]; // [dbuf][hi/lo][row][half*68+k]
    float (*L)[32][68] = (float (*)[32][68])&sbuf[0][0][0][0];   // alias: 2*32*68*4 = 17408 B

    const int tid  = threadIdx.x;
    const int lane = tid & 63;
    const int w    = tid >> 6;            // 0..3
    const int h    = w >> 1;              // K-half
    const int tok0 = blockIdx.x * 32;

    const int mrow = ((w & 1) << 4) + (lane & 15);
    const int aoff = (lane >> 4) << 3;

    f32x4 acc[4];
    #pragma unroll
    for (int nt = 0; nt < 4; ++nt) acc[nt] = (f32x4){0.f, 0.f, 0.f, 0.f};

    // per-thread staging map: p in 0..3, f = tid + p*256
    int sh[4], sr[4], sc[4];
    #pragma unroll
    for (int p = 0; p < 4; ++p) {
        const int f = tid + (p << 8);
        sh[p] = f >> 9;            // K-half of this fragment
        sr[p] = (f >> 4) & 31;     // token row
        sc[p] = (f & 15) << 2;     // k within 64-slice
    }

    float4 nx[4];
    // prologue: load+convert chunk 0 into buf 0
    #pragma unroll
    for (int p = 0; p < 4; ++p)
        nx[p] = *(const float4*)&X[(size_t)(tok0 + sr[p]) * HID + (sh[p] << 11) + sc[p]];
    #pragma unroll
    for (int p = 0; p < 4; ++p) {
        ushort4 hi4, lo4;
        hi4.x = f2bf_rn(nx[p].x); lo4.x = f2bf_rn(nx[p].x - bf2f(hi4.x));
        hi4.y = f2bf_rn(nx[p].y); lo4.y = f2bf_rn(nx[p].y - bf2f(hi4.y));
        hi4.z = f2bf_rn(nx[p].z); lo4.z = f2bf_rn(nx[p].z - bf2f(hi4.z));
        hi4.w = f2bf_rn(nx[p].w); lo4.w = f2bf_rn(nx[p].w - bf2f(hi4.w));
        *(ushort4*)&sbuf[0][0][sr[p]][sh[p] * 68 + sc[p]] = hi4;
        *(ushort4*)&sbuf[0][1][sr[p]][sh[p] * 68 + sc[p]] = lo4;
    }
    __syncthreads();

    for (int c = 0; c < 32; ++c) {
        const int cur = c & 1;
        if (c < 31) {
            #pragma unroll
            for (int p = 0; p < 4; ++p)
                nx[p] = *(const float4*)&X[(size_t)(tok0 + sr[p]) * HID + (sh[p] << 11)
                                           + ((c + 1) << 6) + sc[p]];
        }
        #pragma unroll
        for (int s = 0; s < 2; ++s) {
            const short8_t ah = *(const short8_t*)&sbuf[cur][0][mrow][h * 68 + (s << 5) + aoff];
            const short8_t al = *(const short8_t*)&sbuf[cur][1][mrow][h * 68 + (s << 5) + aoff];
            const int kt = (h << 6) + (c << 1) + s;
            const unsigned short* bb = Bpk + ((size_t)kt << 11) + (lane << 3);
            #pragma unroll
            for (int nt = 0; nt < 4; ++nt) {
                const short8_t bh = *(const short8_t*)(bb + (nt << 9));
                const short8_t bl = *(const short8_t*)(bb + BPK_LO + (nt << 9));
                acc[nt] = __builtin_amdgcn_mfma_f32_16x16x32_bf16(ah, bh, acc[nt], 0, 0, 0);
                acc[nt] = __builtin_amdgcn_mfma_f32_16x16x32_bf16(al, bh, acc[nt], 0, 0, 0);
                acc[nt] = __builtin_amdgcn_mfma_f32_16x16x32_bf16(ah, bl, acc[nt], 0, 0, 0);
            }
        }
        if (c < 31) {
            #pragma unroll
            for (int p = 0; p < 4; ++p) {
                ushort4 hi4, lo4;
                hi4.x = f2bf_rn(nx[p].x); lo4.x = f2bf_rn(nx[p].x - bf2f(hi4.x));
                hi4.y = f2bf_rn(nx[p].y); lo4.y = f2bf_rn(nx[p].y - bf2f(hi4.y));
                hi4.z = f2bf_rn(nx[p].z); lo4.z = f2bf_rn(nx[p].z - bf2f(hi4.z));
                hi4.w = f2bf_rn(nx[p].w); lo4.w = f2bf_rn(nx[p].w - bf2f(hi4.w));
                *(ushort4*)&sbuf[cur ^ 1][0][sr[p]][sh[p] * 68 + sc[p]] = hi4;
                *(ushort4*)&sbuf[cur ^ 1][1][sr[p]][sh[p] * 68 + sc[p]] = lo4;
            }
        }
        __syncthreads();
    }

    // C/D (col=lane&15 -> expert, row=(lane>>4)*4+r -> token) into L[khalf][tok][exp]
    #pragma unroll
    for (int nt = 0; nt < 4; ++nt)
        #pragma unroll
        for (int r = 0; r < 4; ++r)
            L[h][((w & 1) << 4) + ((lane >> 4) << 2) + r][(nt << 4) + (lane & 15)] = acc[nt][r];
    __syncthreads();

    // epilogue: wave w handles tokens w*8 .. w*8+7; lane = expert
    float* outIdx = out;
    float* outW   = out + TOKS * 8;
    int* flagcnt  = (int*)wsf + WS_FLAGCNT;
    int* flaglist = (int*)wsf + WS_FLAGLIST;

    float rp = 0.f;
    #pragma unroll
    for (int tt = 0; tt < 8; ++tt) {
        const int tl = (w << 3) + tt;
        const float lg = L[0][tl][lane] + L[1][tl][lane];

        // bitonic sort-64, descending by (value, then lower index first)
        float v = lg; int idx = lane;
        #pragma unroll
        for (int size = 2; size <= 64; size <<= 1) {
            #pragma unroll
            for (int str = size >> 1; str > 0; str >>= 1) {
                const float ov = __shfl_xor(v, str, 64);
                const int   oi = __shfl_xor(idx, str, 64);
                const bool pb = (ov > v) || (ov == v && oi < idx);      // partner ranks before me
                const bool keepFirst = ((lane & str) == 0) == ((lane & size) == 0);
                if (pb == keepFirst) { v = ov; idx = oi; }
            }
        }

        const float m = __shfl(v, 0, 64);          // max logit
        const float p = __expf(lg - m);
        float s = p;
        #pragma unroll
        for (int o = 32; o; o >>= 1) s += __shfl_xor(s, o, 64);
        const float inv_s = 1.0f / s;
        rp += p * inv_s;

        const float wkv = __expf(v - m) * inv_s;   // my rank's score (lanes 0..8 meaningful)
        float d8 = (lane < 8) ? wkv : 0.f;
        #pragma unroll
        for (int o = 1; o < 8; o <<= 1) d8 += __shfl_xor(d8, o, 64);
        const float invd = 1.0f / (d8 + 1e-20f);
        const float nv = __shfl_down(v, 1, 64);
        const bool flg = __any(lane < 8 && (v - nv) < EPS);

        const int gtok = tok0 + tl;
        if (lane < 8) {
            outIdx[(size_t)gtok * 8 + lane] = (float)idx;
            outW[(size_t)gtok * 8 + lane]   = wkv * invd;
        }
        if (lane == 0) {
            atomicAdd(&wsf[NEXP + idx], 1.0f);     // argmax histogram (sorted lane 0)
            if (flg) {
                const int pos = atomicAdd(flagcnt, 1);
                if (pos < TOKS) flaglist[pos] = gtok;
            }
        }
    }
    atomicAdd(&wsf[lane], rp);
}

// ---------- exact fp64 redo for flagged tokens ----------
__global__ __launch_bounds__(256, 2)
void moe_fix(const float* __restrict__ X, const float* __restrict__ W,
             float* __restrict__ out, float* __restrict__ wsf) {
    __shared__ double red[256];
    const int tid = threadIdx.x;
    const int e   = tid & 63;
    const int kc  = tid >> 6;
    const int nf  = min(*((int*)wsf + WS_FLAGCNT), TOKS);
    const int* flaglist = (const int*)wsf + WS_FLAGLIST;
    float* outIdx = out;
    float* outW   = out + TOKS * 8;

    for (int fi = blockIdx.x; fi < nf; fi += gridDim.x) {
        const int tok = flaglist[fi];
        const float* xrow = X + (size_t)tok * HID + kc * 1024;
        const float* wrow = W + (size_t)e  * HID + kc * 1024;
        double part = 0.0;
        for (int j = 0; j < 1024; j += 4) {
            const float4 xv = *(const float4*)(xrow + j);
            const float4 wv = *(const float4*)(wrow + j);
            part = fma((double)xv.x, (double)wv.x, part);
            part = fma((double)xv.y, (double)wv.y, part);
            part = fma((double)xv.z, (double)wv.z, part);
            part = fma((double)xv.w, (double)wv.w, part);
        }
        red[tid] = part;
        __syncthreads();
        if (tid < 64) {
            const double lg = ((red[tid] + red[64 + tid]) + red[128 + tid]) + red[192 + tid];
            const float lgf = (float)lg;
            float m = lgf;
            #pragma unroll
            for (int o = 32; o; o >>= 1) m = fmaxf(m, __shfl_xor(m, o, 64));
            const float p = __expf(lgf - m);
            float s = p;
            #pragma unroll
            for (int o = 32; o; o >>= 1) s += __shfl_xor(s, o, 64);
            const float inv_s = 1.0f / s;

            double v = lg;
            double bw[8]; int ik[8];
            #pragma unroll
            for (int k = 0; k < 8; ++k) {
                double bv = v; int bi = tid;
                #pragma unroll
                for (int o = 32; o; o >>= 1) {
                    const double ov = __shfl_xor(bv, o, 64);
                    const int    oi = __shfl_xor(bi, o, 64);
                    if (ov > bv || (ov == bv && oi < bi)) { bv = ov; bi = oi; }
                }
                bw[k] = bv; ik[k] = bi;
                if (tid == bi) v = -1.0e300;
            }
            float wk[8]; float denom = 1e-20f;
            #pragma unroll
            for (int k = 0; k < 8; ++k) {
                wk[k] = __expf((float)bw[k] - m) * inv_s; denom += wk[k];
            }
            const float invd = 1.0f / denom;
            const size_t base = (size_t)tok * 8;
            const int oldtop = (int)outIdx[base];
            if (tid < 8) {
                outIdx[base + tid] = (float)ik[tid];
                outW[base + tid]   = wk[tid] * invd;
            }
            if (tid == 0 && ik[0] != oldtop) {
                atomicAdd(&wsf[NEXP + oldtop], -1.0f);
                atomicAdd(&wsf[NEXP + ik[0]],  1.0f);
            }
        }
        __syncthreads();
    }
}

__global__ void moe_final(const float* __restrict__ wsf, float* __restrict__ out) {
    const int e = threadIdx.x;  // 64 threads
    float v = wsf[e] * wsf[NEXP + e];
    #pragma unroll
    for (int o = 32; o; o >>= 1) v += __shfl_xor(v, o, 64);
    if (e == 0)
        out[2 * TOKS * 8] = v * (64.0f / ((float)TOKS * (float)TOKS));
}

// ===== fallback monolith (proven R2 path) for small ws =====
__global__ void moe_init(float* __restrict__ wsf, int n) {
    const int i = blockIdx.x * blockDim.x + threadIdx.x;
    if (i < n) wsf[i] = 0.0f;
}

__global__ void moe_w_cvt(const float* __restrict__ W, double* __restrict__ Wd) {
    const int i = blockIdx.x * blockDim.x + threadIdx.x;
    if (i < NEXP * HID) Wd[i] = (double)W[i];
}

__global__ __launch_bounds__(512, 2)
void moe_mono(const float* __restrict__ X, const double* __restrict__ Wd,
              float* __restrict__ out, float* __restrict__ wsf) {
    __shared__ double xs[64][66];
    __shared__ double L2[64][65];
    const int tid  = threadIdx.x;
    const int lane = tid & 63;
    const int wid  = __builtin_amdgcn_readfirstlane(tid >> 6);
    const int tok0 = blockIdx.x * 64;
    double acc[8] = {0., 0., 0., 0., 0., 0., 0., 0.};
    for (int h0 = 0; h0 < HID; h0 += 64) {
        #pragma unroll
        for (int i = 0; i < 8; ++i) {
            const int li = tid + i * 512;
            xs[li >> 6][li & 63] = (double)X[((size_t)(tok0 + (li >> 6)) << 12) + (h0 + (li & 63))];
        }
        __syncthreads();
        const double* wchunk = Wd + (((size_t)(wid << 3)) << 12) + h0;
        #pragma unroll 2
        for (int hh = 0; hh < 64; hh += 2) {
            const double2 xv = *(const double2*)&xs[lane][hh];
            #pragma unroll
            for (int e = 0; e < 8; ++e) {
                const double* wr = wchunk + (((size_t)e) << 12) + hh;
                acc[e] = fma(xv.x, wr[0], acc[e]);
                acc[e] = fma(xv.y, wr[1], acc[e]);
            }
        }
        __syncthreads();
    }
    #pragma unroll
    for (int e = 0; e < 8; ++e) L2[lane][(wid << 3) + e] = acc[e];
    __syncthreads();
    float* outIdx = out;
    float* outW   = out + (TOKS * 8);
    float rp = 0.0f;
    for (int tt = 0; tt < 8; ++tt) {
        const int t = (wid << 3) + tt;
        const double lg = L2[t][lane];
        const float lgf = (float)lg;
        float m = lgf;
        #pragma unroll
        for (int o = 32; o; o >>= 1) m = fmaxf(m, __shfl_xor(m, o, 64));
        const float p = __expf(lgf - m);
        float s = p;
        #pragma unroll
        for (int o = 32; o; o >>= 1) s += __shfl_xor(s, o, 64);
        const float inv_s = 1.0f / s;
        rp += p * inv_s;
        double v = lg;
        float wk[8]; int ik[8];
        #pragma unroll
        for (int k = 0; k < 8; ++k) {
            double bv = v; int bi = lane;
            #pragma unroll
            for (int o = 32; o; o >>= 1) {
                const double ov = __shfl_xor(bv, o, 64);
                const int    oi = __shfl_xor(bi, o, 64);
                if (ov > bv || (ov == bv && oi < bi)) { bv = ov; bi = oi; }
            }
            wk[k] = __expf((float)bv - m) * inv_s; ik[k] = bi;
            if (lane == bi) v = -1.0e300;
        }
        if (lane == 0) {
            const float denom = (((wk[0]+wk[1])+(wk[2]+wk[3])) +
                                 ((wk[4]+wk[5])+(wk[6]+wk[7]))) + 1e-20f;
            const float invd = 1.0f / denom;
            const size_t base = ((size_t)(tok0 + t)) << 3;
            #pragma unroll
            for (int k = 0; k < 8; ++k) {
                outIdx[base + k] = (float)ik[k];
                outW[base + k]   = wk[k] * invd;
            }
            atomicAdd(&wsf[NEXP + ik[0]], 1.0f);
        }
    }
    atomicAdd(&wsf[lane], rp);
}

extern "C" void kernel_launch(void* const* d_in, const int* in_sizes, int n_in,
                              void* d_out, int out_size, void* d_ws, size_t ws_size,
                              hipStream_t stream) {
    const float* X = (const float*)d_in[0];   // [4,4096,4096] fp32
    const float* W = (const float*)d_in[1];   // [64,4096] fp32
    float* out = (float*)d_out;
    float* wsf = (float*)d_ws;

    const size_t need = 4ull * WS_BPACK + 4ull * BPK_LO;  // slots + Bpack ~ 1.1 MB

    if (ws_size >= need) {
        unsigned short* Bpk = (unsigned short*)(wsf + WS_BPACK);
        moe_prep<<<(NEXP * HID + 255) / 256, 256, 0, stream>>>(W, Bpk, wsf);
        moe_fused<<<TOKS / 32, 256, 0, stream>>>(X, Bpk, out, wsf);
        moe_fix<<<256, 256, 0, stream>>>(X, W, out, wsf);
        moe_final<<<1, 64, 0, stream>>>(wsf, out);
    } else {
        double* Wd = (double*)d_ws;
        float* wsf2 = (float*)(Wd + NEXP * HID);
        moe_w_cvt<<<(NEXP * HID + 255) / 256, 256, 0, stream>>>(W, Wd);
        moe_init<<<1, 256, 0, stream>>>(wsf2, 128);
        moe_mono<<<TOKS / 64, 512, 0, stream>>>(X, Wd, out, wsf2);
        moe_final<<<1, 64, 0, stream>>>(wsf2, out);
    }
}

// Round 7
// 239.804 us; speedup vs baseline: 2.7677x; 1.1539x over previous
//
#include <hip/hip_runtime.h>
#include <hip/hip_bf16.h>

#define TOKS 16384
#define HID  4096
#define NEXP 64
#define EPS  1e-4f   // flag threshold; bf16-split logit err ~3e-6 -> 30x margin

// ===== ws layout (floats) =====
// [0..63] prob sums | [64..127] argmax counts | int@[128] flag count |
// ints [192..192+16384) flag list | [16576) Bpack (1 MB, bf16 hi/lo frag-packed)
#define WS_FLAGCNT  128
#define WS_FLAGLIST 192
#define WS_BPACK    16576
#define BPK_LO      262144   // ushort offset of lo plane inside Bpack

typedef __attribute__((ext_vector_type(8))) short short8_t;
typedef __attribute__((ext_vector_type(4))) float f32x4;

static __device__ __forceinline__ unsigned short f2bf_rn(float x) {
    unsigned u = __builtin_bit_cast(unsigned, x);
    u = (u + 0x7fffu + ((u >> 16) & 1u)) >> 16;
    return (unsigned short)u;
}
static __device__ __forceinline__ float bf2f(unsigned short h) {
    return __builtin_bit_cast(float, (unsigned)h << 16);
}

// ---------- prep: W -> frag-ready bf16 hi/lo pack; zero reduction slots ----------
// Bpack[kt 0..127][nt 0..3][lane 0..63][j 0..7] = Wsplit[n=nt*16+(lane&15)][k=kt*32+8*(lane>>4)+j]
__global__ void moe_prep(const float* __restrict__ W, unsigned short* __restrict__ Bpk,
                         float* __restrict__ wsf) {
    const int idx = blockIdx.x * blockDim.x + threadIdx.x;
    if (idx < 192) wsf[idx] = 0.0f;
    if (idx >= NEXP * HID) return;
    const int n = idx >> 12;
    const int k = idx & 4095;
    const float w = W[idx];
    const unsigned short hi = f2bf_rn(w);
    const unsigned short lo = f2bf_rn(w - bf2f(hi));
    const int kt   = k >> 5;
    const int nt   = n >> 4;
    const int lane = (n & 15) | (((k >> 3) & 3) << 4);
    const int j    = k & 7;
    const int dst  = (((kt << 2) + nt) << 9) + (lane << 3) + j;
    Bpk[dst]          = hi;
    Bpk[BPK_LO + dst] = lo;
}

// ---------- fused: register-direct MFMA GEMM + softmax + bitonic top-8 + flag ----------
// 256 thr = 4 waves; 16 tokens/block; wave w owns K-quarter w (1024 k = 32 kt steps).
// A-frags load straight from global (lane's 32 B is contiguous in k) -> no LDS, no
// barriers, no bank conflicts in the GEMM. Single barrier before the epilogue reduce.
__global__ __launch_bounds__(256, 4)
void moe_fused(const float* __restrict__ X, const unsigned short* __restrict__ Bpk,
               float* __restrict__ out, float* __restrict__ wsf) {
    __shared__ __align__(16) float L[4][16][68];   // [kq][tok][exp(+pad)]

    const int tid  = threadIdx.x;
    const int lane = tid & 63;
    const int w    = tid >> 6;            // K-quarter 0..3
    const int tok0 = blockIdx.x * 16;

    const int mrow = lane & 15;           // token within tile (= A row)
    const int g    = lane >> 4;           // k-subgroup 0..3
    const size_t xbase = (size_t)(tok0 + mrow) * HID + ((size_t)w << 10) + (g << 3);
    const unsigned short* bb0 = Bpk + (((size_t)w << 5) << 11) + (lane << 3);

    f32x4 acc[4];
    #pragma unroll
    for (int nt = 0; nt < 4; ++nt) acc[nt] = (f32x4){0.f, 0.f, 0.f, 0.f};

    #pragma unroll 2
    for (int c = 0; c < 32; ++c) {
        const float4 xa = *(const float4*)&X[xbase + (c << 5)];
        const float4 xb = *(const float4*)&X[xbase + (c << 5) + 4];
        const float xv[8] = {xa.x, xa.y, xa.z, xa.w, xb.x, xb.y, xb.z, xb.w};
        short8_t ah, al;
        #pragma unroll
        for (int j = 0; j < 8; ++j) {
            const unsigned short h = f2bf_rn(xv[j]);
            ah[j] = (short)h;
            al[j] = (short)f2bf_rn(xv[j] - bf2f(h));
        }
        const unsigned short* bb = bb0 + ((size_t)c << 11);
        #pragma unroll
        for (int nt = 0; nt < 4; ++nt) {
            const short8_t bh = *(const short8_t*)(bb + (nt << 9));
            const short8_t bl = *(const short8_t*)(bb + BPK_LO + (nt << 9));
            acc[nt] = __builtin_amdgcn_mfma_f32_16x16x32_bf16(ah, bh, acc[nt], 0, 0, 0);
            acc[nt] = __builtin_amdgcn_mfma_f32_16x16x32_bf16(al, bh, acc[nt], 0, 0, 0);
            acc[nt] = __builtin_amdgcn_mfma_f32_16x16x32_bf16(ah, bl, acc[nt], 0, 0, 0);
        }
    }

    // C/D: col=lane&15 -> expert within ntile, row=(lane>>4)*4+r -> token
    #pragma unroll
    for (int nt = 0; nt < 4; ++nt)
        #pragma unroll
        for (int r = 0; r < 4; ++r)
            L[w][(g << 2) + r][(nt << 4) + mrow] = acc[nt][r];
    __syncthreads();

    // epilogue: wave w handles tokens w*4 .. w*4+3; lane = expert
    float* outIdx = out;
    float* outW   = out + TOKS * 8;
    int* flagcnt  = (int*)wsf + WS_FLAGCNT;
    int* flaglist = (int*)wsf + WS_FLAGLIST;

    float rp = 0.f;
    #pragma unroll
    for (int tt = 0; tt < 4; ++tt) {
        const int tl = (w << 2) + tt;
        const float lg = (L[0][tl][lane] + L[1][tl][lane]) + (L[2][tl][lane] + L[3][tl][lane]);

        // bitonic sort-64, descending by (value, then lower index first)
        float v = lg; int idx = lane;
        #pragma unroll
        for (int size = 2; size <= 64; size <<= 1) {
            #pragma unroll
            for (int str = size >> 1; str > 0; str >>= 1) {
                const float ov = __shfl_xor(v, str, 64);
                const int   oi = __shfl_xor(idx, str, 64);
                const bool pb = (ov > v) || (ov == v && oi < idx);      // partner ranks first
                const bool keepFirst = ((lane & str) == 0) == ((lane & size) == 0);
                if (pb == keepFirst) { v = ov; idx = oi; }
            }
        }

        const float m = __shfl(v, 0, 64);          // max logit
        const float p = __expf(lg - m);
        float s = p;
        #pragma unroll
        for (int o = 32; o; o >>= 1) s += __shfl_xor(s, o, 64);
        const float inv_s = 1.0f / s;
        rp += p * inv_s;

        const float wkv = __expf(v - m) * inv_s;   // my rank's score
        float d8 = (lane < 8) ? wkv : 0.f;
        #pragma unroll
        for (int o = 1; o < 8; o <<= 1) d8 += __shfl_xor(d8, o, 64);
        const float invd = 1.0f / (d8 + 1e-20f);
        const float nv = __shfl_down(v, 1, 64);
        const bool flg = __any(lane < 8 && (v - nv) < EPS);

        const int gtok = tok0 + tl;
        if (lane < 8) {
            outIdx[(size_t)gtok * 8 + lane] = (float)idx;
            outW[(size_t)gtok * 8 + lane]   = wkv * invd;
        }
        if (lane == 0) {
            atomicAdd(&wsf[NEXP + idx], 1.0f);     // argmax histogram
            if (flg) {
                const int pos = atomicAdd(flagcnt, 1);
                if (pos < TOKS) flaglist[pos] = gtok;
            }
        }
    }
    atomicAdd(&wsf[lane], rp);
}

// ---------- exact fp64 redo for flagged tokens ----------
__global__ __launch_bounds__(256, 2)
void moe_fix(const float* __restrict__ X, const float* __restrict__ W,
             float* __restrict__ out, float* __restrict__ wsf) {
    __shared__ double red[256];
    const int tid = threadIdx.x;
    const int e   = tid & 63;
    const int kc  = tid >> 6;
    const int nf  = min(*((int*)wsf + WS_FLAGCNT), TOKS);
    const int* flaglist = (const int*)wsf + WS_FLAGLIST;
    float* outIdx = out;
    float* outW   = out + TOKS * 8;

    for (int fi = blockIdx.x; fi < nf; fi += gridDim.x) {
        const int tok = flaglist[fi];
        const float* xrow = X + (size_t)tok * HID + kc * 1024;
        const float* wrow = W + (size_t)e  * HID + kc * 1024;
        double part = 0.0;
        for (int j = 0; j < 1024; j += 4) {
            const float4 xv = *(const float4*)(xrow + j);
            const float4 wv = *(const float4*)(wrow + j);
            part = fma((double)xv.x, (double)wv.x, part);
            part = fma((double)xv.y, (double)wv.y, part);
            part = fma((double)xv.z, (double)wv.z, part);
            part = fma((double)xv.w, (double)wv.w, part);
        }
        red[tid] = part;
        __syncthreads();
        if (tid < 64) {
            const double lg = ((red[tid] + red[64 + tid]) + red[128 + tid]) + red[192 + tid];
            const float lgf = (float)lg;
            float m = lgf;
            #pragma unroll
            for (int o = 32; o; o >>= 1) m = fmaxf(m, __shfl_xor(m, o, 64));
            const float p = __expf(lgf - m);
            float s = p;
            #pragma unroll
            for (int o = 32; o; o >>= 1) s += __shfl_xor(s, o, 64);
            const float inv_s = 1.0f / s;

            double v = lg;
            double bw[8]; int ik[8];
            #pragma unroll
            for (int k = 0; k < 8; ++k) {
                double bv = v; int bi = tid;
                #pragma unroll
                for (int o = 32; o; o >>= 1) {
                    const double ov = __shfl_xor(bv, o, 64);
                    const int    oi = __shfl_xor(bi, o, 64);
                    if (ov > bv || (ov == bv && oi < bi)) { bv = ov; bi = oi; }
                }
                bw[k] = bv; ik[k] = bi;
                if (tid == bi) v = -1.0e300;
            }
            float wk[8]; float denom = 1e-20f;
            #pragma unroll
            for (int k = 0; k < 8; ++k) {
                wk[k] = __expf((float)bw[k] - m) * inv_s; denom += wk[k];
            }
            const float invd = 1.0f / denom;
            const size_t base = (size_t)tok * 8;
            const int oldtop = (int)outIdx[base];
            if (tid < 8) {
                outIdx[base + tid] = (float)ik[tid];
                outW[base + tid]   = wk[tid] * invd;
            }
            if (tid == 0 && ik[0] != oldtop) {
                atomicAdd(&wsf[NEXP + oldtop], -1.0f);
                atomicAdd(&wsf[NEXP + ik[0]],  1.0f);
            }
        }
        __syncthreads();
    }
}

__global__ void moe_final(const float* __restrict__ wsf, float* __restrict__ out) {
    const int e = threadIdx.x;  // 64 threads
    float v = wsf[e] * wsf[NEXP + e];
    #pragma unroll
    for (int o = 32; o; o >>= 1) v += __shfl_xor(v, o, 64);
    if (e == 0)
        out[2 * TOKS * 8] = v * (64.0f / ((float)TOKS * (float)TOKS));
}

// ===== fallback monolith (proven R2 path) for small ws =====
__global__ void moe_init(float* __restrict__ wsf, int n) {
    const int i = blockIdx.x * blockDim.x + threadIdx.x;
    if (i < n) wsf[i] = 0.0f;
}

__global__ void moe_w_cvt(const float* __restrict__ W, double* __restrict__ Wd) {
    const int i = blockIdx.x * blockDim.x + threadIdx.x;
    if (i < NEXP * HID) Wd[i] = (double)W[i];
}

__global__ __launch_bounds__(512, 2)
void moe_mono(const float* __restrict__ X, const double* __restrict__ Wd,
              float* __restrict__ out, float* __restrict__ wsf) {
    __shared__ double xs[64][66];
    __shared__ double L2[64][65];
    const int tid  = threadIdx.x;
    const int lane = tid & 63;
    const int wid  = __builtin_amdgcn_readfirstlane(tid >> 6);
    const int tok0 = blockIdx.x * 64;
    double acc[8] = {0., 0., 0., 0., 0., 0., 0., 0.};
    for (int h0 = 0; h0 < HID; h0 += 64) {
        #pragma unroll
        for (int i = 0; i < 8; ++i) {
            const int li = tid + i * 512;
            xs[li >> 6][li & 63] = (double)X[((size_t)(tok0 + (li >> 6)) << 12) + (h0 + (li & 63))];
        }
        __syncthreads();
        const double* wchunk = Wd + (((size_t)(wid << 3)) << 12) + h0;
        #pragma unroll 2
        for (int hh = 0; hh < 64; hh += 2) {
            const double2 xv = *(const double2*)&xs[lane][hh];
            #pragma unroll
            for (int e = 0; e < 8; ++e) {
                const double* wr = wchunk + (((size_t)e) << 12) + hh;
                acc[e] = fma(xv.x, wr[0], acc[e]);
                acc[e] = fma(xv.y, wr[1], acc[e]);
            }
        }
        __syncthreads();
    }
    #pragma unroll
    for (int e = 0; e < 8; ++e) L2[lane][(wid << 3) + e] = acc[e];
    __syncthreads();
    float* outIdx = out;
    float* outW   = out + (TOKS * 8);
    float rp = 0.0f;
    for (int tt = 0; tt < 8; ++tt) {
        const int t = (wid << 3) + tt;
        const double lg = L2[t][lane];
        const float lgf = (float)lg;
        float m = lgf;
        #pragma unroll
        for (int o = 32; o; o >>= 1) m = fmaxf(m, __shfl_xor(m, o, 64));
        const float p = __expf(lgf - m);
        float s = p;
        #pragma unroll
        for (int o = 32; o; o >>= 1) s += __shfl_xor(s, o, 64);
        const float inv_s = 1.0f / s;
        rp += p * inv_s;
        double v = lg;
        float wk[8]; int ik[8];
        #pragma unroll
        for (int k = 0; k < 8; ++k) {
            double bv = v; int bi = lane;
            #pragma unroll
            for (int o = 32; o; o >>= 1) {
                const double ov = __shfl_xor(bv, o, 64);
                const int    oi = __shfl_xor(bi, o, 64);
                if (ov > bv || (ov == bv && oi < bi)) { bv = ov; bi = oi; }
            }
            wk[k] = __expf((float)bv - m) * inv_s; ik[k] = bi;
            if (lane == bi) v = -1.0e300;
        }
        if (lane == 0) {
            const float denom = (((wk[0]+wk[1])+(wk[2]+wk[3])) +
                                 ((wk[4]+wk[5])+(wk[6]+wk[7]))) + 1e-20f;
            const float invd = 1.0f / denom;
            const size_t base = ((size_t)(tok0 + t)) << 3;
            #pragma unroll
            for (int k = 0; k < 8; ++k) {
                outIdx[base + k] = (float)ik[k];
                outW[base + k]   = wk[k] * invd;
            }
            atomicAdd(&wsf[NEXP + ik[0]], 1.0f);
        }
    }
    atomicAdd(&wsf[lane], rp);
}

extern "C" void kernel_launch(void* const* d_in, const int* in_sizes, int n_in,
                              void* d_out, int out_size, void* d_ws, size_t ws_size,
                              hipStream_t stream) {
    const float* X = (const float*)d_in[0];   // [4,4096,4096] fp32
    const float* W = (const float*)d_in[1];   // [64,4096] fp32
    float* out = (float*)d_out;
    float* wsf = (float*)d_ws;

    const size_t need = 4ull * WS_BPACK + 4ull * BPK_LO;  // slots + Bpack ~ 1.1 MB

    if (ws_size >= need) {
        unsigned short* Bpk = (unsigned short*)(wsf + WS_BPACK);
        moe_prep<<<(NEXP * HID + 255) / 256, 256, 0, stream>>>(W, Bpk, wsf);
        moe_fused<<<TOKS / 16, 256, 0, stream>>>(X, Bpk, out, wsf);
        moe_fix<<<256, 256, 0, stream>>>(X, W, out, wsf);
        moe_final<<<1, 64, 0, stream>>>(wsf, out);
    } else {
        double* Wd = (double*)d_ws;
        float* wsf2 = (float*)(Wd + NEXP * HID);
        moe_w_cvt<<<(NEXP * HID + 255) / 256, 256, 0, stream>>>(W, Wd);
        moe_init<<<1, 256, 0, stream>>>(wsf2, 128);
        moe_mono<<<TOKS / 64, 512, 0, stream>>>(X, Wd, out, wsf2);
        moe_final<<<1, 64, 0, stream>>>(wsf2, out);
    }
}